// Round 2
// baseline (1191.779 us; speedup 1.0000x reference)
//
#include <hip/hip_runtime.h>
#include <hip/hip_bf16.h>
#include <cstdint>
#include <cstddef>

// BaseNet: B=262144 samples, d=512.
// H = relu(reshape(combined,[2B,512]) @ W_in + b_in)   [2B,128]
// m[s] = 0.5*(H[2s]+H[2s+1])                           [B,128]
// g1 = relu(m @ W1 + b1); g2 = relu(g1 @ W2 + b2)      [B,128],[B,64]
// out = sigmoid(g2 . (W_out[:64]+W_out[64:]) + b_out)  [B]

#define NROWS   524288   // 2B
#define NSAMP   262144   // B

typedef __attribute__((ext_vector_type(8))) short  bf16x8;
typedef __attribute__((ext_vector_type(4))) float  f32x4;

__device__ __forceinline__ unsigned short f2bf(float f) {
    unsigned u = __float_as_uint(f);
    u += 0x7fffu + ((u >> 16) & 1u);   // round-to-nearest-even
    return (unsigned short)(u >> 16);
}

__device__ __forceinline__ bf16x8 cvt8(f32x4 lo, f32x4 hi) {
    bf16x8 r;
    r[0] = (short)f2bf(lo[0]); r[1] = (short)f2bf(lo[1]);
    r[2] = (short)f2bf(lo[2]); r[3] = (short)f2bf(lo[3]);
    r[4] = (short)f2bf(hi[0]); r[5] = (short)f2bf(hi[1]);
    r[6] = (short)f2bf(hi[2]); r[7] = (short)f2bf(hi[3]);
    return r;
}

// ---------------- workspace layout (bytes) ----------------
#define WS_M     0                       // [B][128] bf16 = 67108864 B
#define WS_WIN   67108864                // Win frags: 16*8*64*8 bf16 = 131072 B
#define WS_W1    67239936                // W1 frags:  4*8*64*8 bf16 = 32768 B
#define WS_W2    67272704                // W2 frags:  4*4*64*8 bf16 = 16384 B
#define WS_WEFF  67289088                // 64 floats

// ---------------- prep: pack weights to MFMA B-fragment layout ----------------
// Standard B-frag (16x16x32): lane l holds B[k=(l>>4)*8+j][col=l&15], j=0..7.
// fWin uses a PERMUTED k mapping to match kA's coalesced A loads:
//   slot j of lane (lg=l>>4) holds k = (j<4) ? lg*4+j : 16+lg*4+(j-4)  (within 32-group)
// dst layout: [kt][nt][lane][8] bf16.
__global__ void prep_kernel(const float* __restrict__ W_in,
                            const float* __restrict__ W1,
                            const float* __restrict__ W2,
                            const float* __restrict__ W_out,
                            unsigned short* __restrict__ fWin,
                            unsigned short* __restrict__ fW1,
                            unsigned short* __restrict__ fW2,
                            float* __restrict__ weff) {
    int tid = blockIdx.x * 256 + threadIdx.x;
    if (tid < 65536) {                       // W_in [512][128]: KT=16, NT=8 (permuted k)
        int e = tid;
        int j = e & 7, l = (e >> 3) & 63, rest = e >> 9;
        int n = rest & 7, kt = rest >> 3;
        int lg = l >> 4;
        int kin = (j < 4) ? (lg * 4 + j) : (16 + lg * 4 + (j - 4));
        int k = kt * 32 + kin;
        int col = n * 16 + (l & 15);
        fWin[e] = f2bf(W_in[k * 128 + col]);
    } else if (tid < 65536 + 16384) {        // W1 [128][128]: KT=4, NT=8 (standard)
        int e = tid - 65536;
        int j = e & 7, l = (e >> 3) & 63, rest = e >> 9;
        int n = rest & 7, kt = rest >> 3;
        int k = kt * 32 + ((l >> 4) << 3) + j;
        int col = n * 16 + (l & 15);
        fW1[e] = f2bf(W1[k * 128 + col]);
    } else if (tid < 65536 + 16384 + 8192) { // W2 [128][64]: KT=4, NT=4 (standard)
        int e = tid - 65536 - 16384;
        int j = e & 7, l = (e >> 3) & 63, rest = e >> 9;
        int n = rest & 3, kt = rest >> 2;
        int k = kt * 32 + ((l >> 4) << 3) + j;
        int col = n * 16 + (l & 15);
        fW2[e] = f2bf(W2[k * 64 + col]);
    } else if (tid < 65536 + 16384 + 8192 + 64) {
        int c = tid - (65536 + 16384 + 8192);
        weff[c] = W_out[c] + W_out[64 + c];
    }
}

// ---------------- kernel A: big GEMM + bias/relu + node-mean -> M (bf16) -----
// 256 persistent blocks (1/CU, LDS=128KB), 1024 threads = 16 waves (4/SIMD),
// each wave owns one 16-row tile. A loads are 64B-contiguous per row via the
// permuted-k fragment mapping (matching fWin packing above).
__global__ void __launch_bounds__(1024)
kA(const float* __restrict__ A,              // [2B][512] fp32 (= combined)
   const unsigned short* __restrict__ fWin,  // frag layout (permuted k)
   const float* __restrict__ b_in,
   unsigned short* __restrict__ M) {         // [B][128] bf16
    __shared__ unsigned short lwin[65536];   // 128 KB
    {
        const f32x4* src = (const f32x4*)fWin;
        f32x4* dst = (f32x4*)lwin;
        int tid = threadIdx.x;
        #pragma unroll
        for (int i = 0; i < 8; ++i) dst[i * 1024 + tid] = src[i * 1024 + tid];
    }
    __syncthreads();
    const int w = threadIdx.x >> 6, l = threadIdx.x & 63;
    const int lr = l & 15, lg = l >> 4;
    float binv[8];
    #pragma unroll
    for (int n = 0; n < 8; ++n) binv[n] = b_in[n * 16 + lr];

    for (int t = blockIdx.x; t < NROWS / 256; t += 256) {
        const size_t rowbase = (size_t)t * 256 + (size_t)w * 16;
        // lane base: row rowbase+lr, float offset lg*4 (16B). Each (ks,half)
        // load covers 16 rows x 64B contiguous across lg=0..3.
        const float* a = A + (rowbase + lr) * 512 + lg * 4;

        f32x4 acc[8];
        #pragma unroll
        for (int n = 0; n < 8; ++n) acc[n] = (f32x4){0.f, 0.f, 0.f, 0.f};

        // double-buffered register staging: [buf][ks][half]
        f32x4 st[2][4][2];
        #pragma unroll
        for (int ks = 0; ks < 4; ++ks) {
            st[0][ks][0] = *(const f32x4*)(a + ks * 32);
            st[0][ks][1] = *(const f32x4*)(a + ks * 32 + 16);
        }
        #pragma unroll
        for (int c = 0; c < 4; ++c) {
            const int cur = c & 1, nxt = cur ^ 1;
            if (c < 3) {
                #pragma unroll
                for (int ks = 0; ks < 4; ++ks) {
                    st[nxt][ks][0] = *(const f32x4*)(a + (c + 1) * 128 + ks * 32);
                    st[nxt][ks][1] = *(const f32x4*)(a + (c + 1) * 128 + ks * 32 + 16);
                }
            }
            #pragma unroll
            for (int ks = 0; ks < 4; ++ks) {
                const int kg = c * 4 + ks;
                bf16x8 af = cvt8(st[cur][ks][0], st[cur][ks][1]);
                #pragma unroll
                for (int n = 0; n < 8; ++n) {
                    bf16x8 bf = *(const bf16x8*)&lwin[((kg * 8 + n) * 64 + l) * 8];
                    acc[n] = __builtin_amdgcn_mfma_f32_16x16x32_bf16(af, bf, acc[n], 0, 0, 0);
                }
            }
        }
        // epilogue: bias + relu + pair-mean -> bf16 M
        // C layout: row=(l>>4)*4+r, col=l&15 within 16x16 tile.
        const size_t smp = (rowbase >> 1) + 2 * lg;
        #pragma unroll
        for (int n = 0; n < 8; ++n) {
            const float b = binv[n];
            float h0 = fmaxf(acc[n][0] + b, 0.f);
            float h1 = fmaxf(acc[n][1] + b, 0.f);
            float h2 = fmaxf(acc[n][2] + b, 0.f);
            float h3 = fmaxf(acc[n][3] + b, 0.f);
            M[smp * 128 + n * 16 + lr]       = f2bf(0.5f * (h0 + h1));
            M[(smp + 1) * 128 + n * 16 + lr] = f2bf(0.5f * (h2 + h3));
        }
    }
}

// ---------------- kernel B: m -> g1 -> g2 -> sigmoid(score) -----------------
// 512 blocks (2/CU, LDS=64KB), 4 waves x 16 samples per tile-iter.
__global__ void __launch_bounds__(256, 2)
kB(const unsigned short* __restrict__ M,
   const unsigned short* __restrict__ fW1,
   const unsigned short* __restrict__ fW2,
   const float* __restrict__ weff,
   const float* __restrict__ b1,
   const float* __restrict__ b2,
   const float* __restrict__ b_out,
   float* __restrict__ out) {
    __shared__ unsigned short lw1[16384];       // 32 KB
    __shared__ unsigned short lw2[8192];        // 16 KB
    __shared__ unsigned short bounce[4][2048];  // 4 waves x 4 KB
    {
        int tid = threadIdx.x;
        const f32x4* s1 = (const f32x4*)fW1;
        f32x4* d1 = (f32x4*)lw1;
        #pragma unroll
        for (int i = 0; i < 8; ++i) d1[i * 256 + tid] = s1[i * 256 + tid];
        const f32x4* s2 = (const f32x4*)fW2;
        f32x4* d2 = (f32x4*)lw2;
        #pragma unroll
        for (int i = 0; i < 4; ++i) d2[i * 256 + tid] = s2[i * 256 + tid];
    }
    __syncthreads();
    const int w = threadIdx.x >> 6, l = threadIdx.x & 63;
    const int lr = l & 15, lg = l >> 4;
    float b1v[8], b2v[4], wev[4];
    #pragma unroll
    for (int n = 0; n < 8; ++n) b1v[n] = b1[n * 16 + lr];
    #pragma unroll
    for (int n = 0; n < 4; ++n) { b2v[n] = b2[n * 16 + lr]; wev[n] = weff[n * 16 + lr]; }
    const float bo = b_out[0];

    for (int t = blockIdx.x; t < NSAMP / 64; t += 512) {
        const int s0 = t * 64 + w * 16;
        // ---- layer 2: g1 = relu(m @ W1 + b1) via MFMA ----
        f32x4 acc1[8];
        #pragma unroll
        for (int n = 0; n < 8; ++n) acc1[n] = (f32x4){0.f, 0.f, 0.f, 0.f};
        const unsigned short* arow = M + (size_t)(s0 + lr) * 128 + lg * 8;
        #pragma unroll
        for (int ks = 0; ks < 4; ++ks) {
            bf16x8 af = *(const bf16x8*)(arow + ks * 32);
            #pragma unroll
            for (int n = 0; n < 8; ++n) {
                bf16x8 bf = *(const bf16x8*)&lw1[((ks * 8 + n) * 64 + l) * 8];
                acc1[n] = __builtin_amdgcn_mfma_f32_16x16x32_bf16(af, bf, acc1[n], 0, 0, 0);
            }
        }
        // bounce g1 (C layout) -> LDS row-major [16][128] bf16, XOR-swizzled
        #pragma unroll
        for (int n = 0; n < 8; ++n) {
            #pragma unroll
            for (int r = 0; r < 4; ++r) {
                float g = fmaxf(acc1[n][r] + b1v[n], 0.f);
                int row = lg * 4 + r, col = n * 16 + lr;
                int boff = row * 256 + ((col * 2) ^ ((row & 7) << 4));
                bounce[w][boff >> 1] = f2bf(g);
            }
        }
        // ---- layer 3: g2 = relu(g1 @ W2 + b2) ----
        f32x4 acc2[4];
        #pragma unroll
        for (int n = 0; n < 4; ++n) acc2[n] = (f32x4){0.f, 0.f, 0.f, 0.f};
        #pragma unroll
        for (int ks = 0; ks < 4; ++ks) {
            int roff = lr * 256 + ((ks * 64 + lg * 16) ^ ((lr & 7) << 4));
            bf16x8 af2 = *(const bf16x8*)((const char*)&bounce[w][0] + roff);
            #pragma unroll
            for (int n = 0; n < 4; ++n) {
                bf16x8 bf = *(const bf16x8*)&lw2[((ks * 4 + n) * 64 + l) * 8];
                acc2[n] = __builtin_amdgcn_mfma_f32_16x16x32_bf16(af2, bf, acc2[n], 0, 0, 0);
            }
        }
        // ---- layer 4: dot with w_eff, reduce over 16 lanes, sigmoid ----
        float p0 = 0.f, p1 = 0.f, p2 = 0.f, p3 = 0.f;
        #pragma unroll
        for (int n = 0; n < 4; ++n) {
            p0 += fmaxf(acc2[n][0] + b2v[n], 0.f) * wev[n];
            p1 += fmaxf(acc2[n][1] + b2v[n], 0.f) * wev[n];
            p2 += fmaxf(acc2[n][2] + b2v[n], 0.f) * wev[n];
            p3 += fmaxf(acc2[n][3] + b2v[n], 0.f) * wev[n];
        }
        #pragma unroll
        for (int m = 1; m < 16; m <<= 1) {
            p0 += __shfl_xor(p0, m);
            p1 += __shfl_xor(p1, m);
            p2 += __shfl_xor(p2, m);
            p3 += __shfl_xor(p3, m);
        }
        float s0f = 1.f / (1.f + expf(-(p0 + bo)));
        float s1f = 1.f / (1.f + expf(-(p1 + bo)));
        float s2f = 1.f / (1.f + expf(-(p2 + bo)));
        float s3f = 1.f / (1.f + expf(-(p3 + bo)));
        if (lr < 4) {
            float v = (lr == 0) ? s0f : (lr == 1) ? s1f : (lr == 2) ? s2f : s3f;
            out[s0 + lg * 4 + lr] = v;
        }
    }
}

// ---------------- host launcher ----------------
extern "C" void kernel_launch(void* const* d_in, const int* in_sizes, int n_in,
                              void* d_out, int out_size, void* d_ws, size_t ws_size,
                              hipStream_t stream) {
    const float* combined = (const float*)d_in[0];
    const float* W_in  = (const float*)d_in[1];
    const float* b_in  = (const float*)d_in[2];
    const float* W1    = (const float*)d_in[3];
    const float* b1    = (const float*)d_in[4];
    const float* W2    = (const float*)d_in[5];
    const float* b2    = (const float*)d_in[6];
    const float* W_out = (const float*)d_in[7];
    const float* b_out = (const float*)d_in[8];
    float* out = (float*)d_out;

    char* ws = (char*)d_ws;
    unsigned short* M    = (unsigned short*)(ws + WS_M);
    unsigned short* fWin = (unsigned short*)(ws + WS_WIN);
    unsigned short* fW1  = (unsigned short*)(ws + WS_W1);
    unsigned short* fW2  = (unsigned short*)(ws + WS_W2);
    float* weff          = (float*)(ws + WS_WEFF);

    prep_kernel<<<(65536 + 16384 + 8192 + 64 + 255) / 256, 256, 0, stream>>>(
        W_in, W1, W2, W_out, fWin, fW1, fW2, weff);
    kA<<<256, 1024, 0, stream>>>(combined, fWin, b_in, M);
    kB<<<512, 256, 0, stream>>>(M, fW1, fW2, weff, b1, b2, b_out, out);
}

// Round 3
// 1191.306 us; speedup vs baseline: 1.0004x; 1.0004x over previous
//
#include <hip/hip_runtime.h>
#include <hip/hip_bf16.h>
#include <cstdint>
#include <cstddef>

// BaseNet: B=262144 samples, d=512.
// H = relu(reshape(combined,[2B,512]) @ W_in + b_in)   [2B,128]
// m[s] = 0.5*(H[2s]+H[2s+1])                           [B,128]
// g1 = relu(m @ W1 + b1); g2 = relu(g1 @ W2 + b2)      [B,128],[B,64]
// out = sigmoid(g2 . (W_out[:64]+W_out[64:]) + b_out)  [B]

#define NROWS   524288   // 2B
#define NSAMP   262144   // B

typedef __attribute__((ext_vector_type(8))) short  bf16x8;
typedef __attribute__((ext_vector_type(4))) float  f32x4;

__device__ __forceinline__ unsigned short f2bf(float f) {
    unsigned u = __float_as_uint(f);
    u += 0x7fffu + ((u >> 16) & 1u);   // round-to-nearest-even
    return (unsigned short)(u >> 16);
}

__device__ __forceinline__ bf16x8 cvt8(f32x4 lo, f32x4 hi) {
    bf16x8 r;
    r[0] = (short)f2bf(lo[0]); r[1] = (short)f2bf(lo[1]);
    r[2] = (short)f2bf(lo[2]); r[3] = (short)f2bf(lo[3]);
    r[4] = (short)f2bf(hi[0]); r[5] = (short)f2bf(hi[1]);
    r[6] = (short)f2bf(hi[2]); r[7] = (short)f2bf(hi[3]);
    return r;
}

// ---------------- workspace layout (bytes) ----------------
#define WS_M     0                       // [B][128] bf16 = 67108864 B
#define WS_WIN   67108864                // Win frags: 16*8*64*8 bf16 = 131072 B
#define WS_W1    67239936                // W1 frags:  4*8*64*8 bf16 = 32768 B
#define WS_W2    67272704                // W2 frags:  4*4*64*8 bf16 = 16384 B
#define WS_WEFF  67289088                // 64 floats

// ---------------- prep: pack weights to MFMA B-fragment layout ----------------
// Standard B-frag (16x16x32): lane l holds B[k=(l>>4)*8+j][col=l&15], j=0..7.
// fWin uses a PERMUTED k mapping to match kA's coalesced A loads:
//   slot j of lane (lg=l>>4) holds k = (j<4) ? lg*4+j : 16+lg*4+(j-4)  (within 32-group)
// dst layout: [kt][nt][lane][8] bf16.
__global__ void prep_kernel(const float* __restrict__ W_in,
                            const float* __restrict__ W1,
                            const float* __restrict__ W2,
                            const float* __restrict__ W_out,
                            unsigned short* __restrict__ fWin,
                            unsigned short* __restrict__ fW1,
                            unsigned short* __restrict__ fW2,
                            float* __restrict__ weff) {
    int tid = blockIdx.x * 256 + threadIdx.x;
    if (tid < 65536) {                       // W_in [512][128]: KT=16, NT=8 (permuted k)
        int e = tid;
        int j = e & 7, l = (e >> 3) & 63, rest = e >> 9;
        int n = rest & 7, kt = rest >> 3;
        int lg = l >> 4;
        int kin = (j < 4) ? (lg * 4 + j) : (16 + lg * 4 + (j - 4));
        int k = kt * 32 + kin;
        int col = n * 16 + (l & 15);
        fWin[e] = f2bf(W_in[k * 128 + col]);
    } else if (tid < 65536 + 16384) {        // W1 [128][128]: KT=4, NT=8 (standard)
        int e = tid - 65536;
        int j = e & 7, l = (e >> 3) & 63, rest = e >> 9;
        int n = rest & 7, kt = rest >> 3;
        int k = kt * 32 + ((l >> 4) << 3) + j;
        int col = n * 16 + (l & 15);
        fW1[e] = f2bf(W1[k * 128 + col]);
    } else if (tid < 65536 + 16384 + 8192) { // W2 [128][64]: KT=4, NT=4 (standard)
        int e = tid - 65536 - 16384;
        int j = e & 7, l = (e >> 3) & 63, rest = e >> 9;
        int n = rest & 3, kt = rest >> 2;
        int k = kt * 32 + ((l >> 4) << 3) + j;
        int col = n * 16 + (l & 15);
        fW2[e] = f2bf(W2[k * 64 + col]);
    } else if (tid < 65536 + 16384 + 8192 + 64) {
        int c = tid - (65536 + 16384 + 8192);
        weff[c] = W_out[c] + W_out[64 + c];
    }
}

// ---------------- kernel A: big GEMM + bias/relu + node-mean -> M (bf16) -----
// 256 persistent blocks (1/CU, LDS=128KB), 1024 threads = 16 waves (4/SIMD).
// __launch_bounds__(1024, 4): 4 waves/EU -> 1 block/CU, 128-VGPR budget
// (round-2 lesson: without the 2nd arg the compiler capped at 64 VGPR and
// spilled the whole staging buffer -> 2.44 GB FETCH, 2.1 TB/s).
// A loads are 64B-contiguous per row via the permuted-k fragment mapping.
// Staging double-buffers at 2-kg (64 float) granularity: st[2][2][2] = 32 VGPR.
__global__ void __launch_bounds__(1024, 4)
kA(const float* __restrict__ A,              // [2B][512] fp32 (= combined)
   const unsigned short* __restrict__ fWin,  // frag layout (permuted k)
   const float* __restrict__ b_in,
   unsigned short* __restrict__ M) {         // [B][128] bf16
    __shared__ unsigned short lwin[65536];   // 128 KB
    {
        const f32x4* src = (const f32x4*)fWin;
        f32x4* dst = (f32x4*)lwin;
        int tid = threadIdx.x;
        #pragma unroll
        for (int i = 0; i < 8; ++i) dst[i * 1024 + tid] = src[i * 1024 + tid];
    }
    __syncthreads();
    const int w = threadIdx.x >> 6, l = threadIdx.x & 63;
    const int lr = l & 15, lg = l >> 4;
    float binv[8];
    #pragma unroll
    for (int n = 0; n < 8; ++n) binv[n] = b_in[n * 16 + lr];

    for (int t = blockIdx.x; t < NROWS / 256; t += 256) {
        const size_t rowbase = (size_t)t * 256 + (size_t)w * 16;
        // lane base: row rowbase+lr, float offset lg*4 (16B). Each (ks,half)
        // load covers 16 rows x 64B contiguous across lg=0..3.
        const float* a = A + (rowbase + lr) * 512 + lg * 4;

        f32x4 acc[8];
        #pragma unroll
        for (int n = 0; n < 8; ++n) acc[n] = (f32x4){0.f, 0.f, 0.f, 0.f};

        // double-buffered register staging at 2-kg depth: [buf][ks][half]
        f32x4 st[2][2][2];
        #pragma unroll
        for (int ks = 0; ks < 2; ++ks) {
            st[0][ks][0] = *(const f32x4*)(a + ks * 32);
            st[0][ks][1] = *(const f32x4*)(a + ks * 32 + 16);
        }
        #pragma unroll
        for (int c = 0; c < 8; ++c) {           // 8 chunks x 64 floats
            const int cur = c & 1, nxt = cur ^ 1;
            if (c < 7) {
                #pragma unroll
                for (int ks = 0; ks < 2; ++ks) {
                    st[nxt][ks][0] = *(const f32x4*)(a + (c + 1) * 64 + ks * 32);
                    st[nxt][ks][1] = *(const f32x4*)(a + (c + 1) * 64 + ks * 32 + 16);
                }
            }
            #pragma unroll
            for (int ks = 0; ks < 2; ++ks) {
                const int kg = c * 2 + ks;
                bf16x8 af = cvt8(st[cur][ks][0], st[cur][ks][1]);
                #pragma unroll
                for (int n = 0; n < 8; ++n) {
                    bf16x8 bf = *(const bf16x8*)&lwin[((kg * 8 + n) * 64 + l) * 8];
                    acc[n] = __builtin_amdgcn_mfma_f32_16x16x32_bf16(af, bf, acc[n], 0, 0, 0);
                }
            }
        }
        // epilogue: bias + relu + pair-mean -> bf16 M
        // C layout: row=(l>>4)*4+r, col=l&15 within 16x16 tile.
        const size_t smp = (rowbase >> 1) + 2 * lg;
        #pragma unroll
        for (int n = 0; n < 8; ++n) {
            const float b = binv[n];
            float h0 = fmaxf(acc[n][0] + b, 0.f);
            float h1 = fmaxf(acc[n][1] + b, 0.f);
            float h2 = fmaxf(acc[n][2] + b, 0.f);
            float h3 = fmaxf(acc[n][3] + b, 0.f);
            M[smp * 128 + n * 16 + lr]       = f2bf(0.5f * (h0 + h1));
            M[(smp + 1) * 128 + n * 16 + lr] = f2bf(0.5f * (h2 + h3));
        }
    }
}

// ---------------- kernel B: m -> g1 -> g2 -> sigmoid(score) -----------------
// 512 blocks (2/CU, LDS=64KB), 4 waves x 16 samples per tile-iter.
__global__ void __launch_bounds__(256, 2)
kB(const unsigned short* __restrict__ M,
   const unsigned short* __restrict__ fW1,
   const unsigned short* __restrict__ fW2,
   const float* __restrict__ weff,
   const float* __restrict__ b1,
   const float* __restrict__ b2,
   const float* __restrict__ b_out,
   float* __restrict__ out) {
    __shared__ unsigned short lw1[16384];       // 32 KB
    __shared__ unsigned short lw2[8192];        // 16 KB
    __shared__ unsigned short bounce[4][2048];  // 4 waves x 4 KB
    {
        int tid = threadIdx.x;
        const f32x4* s1 = (const f32x4*)fW1;
        f32x4* d1 = (f32x4*)lw1;
        #pragma unroll
        for (int i = 0; i < 8; ++i) d1[i * 256 + tid] = s1[i * 256 + tid];
        const f32x4* s2 = (const f32x4*)fW2;
        f32x4* d2 = (f32x4*)lw2;
        #pragma unroll
        for (int i = 0; i < 4; ++i) d2[i * 256 + tid] = s2[i * 256 + tid];
    }
    __syncthreads();
    const int w = threadIdx.x >> 6, l = threadIdx.x & 63;
    const int lr = l & 15, lg = l >> 4;
    float b1v[8], b2v[4], wev[4];
    #pragma unroll
    for (int n = 0; n < 8; ++n) b1v[n] = b1[n * 16 + lr];
    #pragma unroll
    for (int n = 0; n < 4; ++n) { b2v[n] = b2[n * 16 + lr]; wev[n] = weff[n * 16 + lr]; }
    const float bo = b_out[0];

    for (int t = blockIdx.x; t < NSAMP / 64; t += 512) {
        const int s0 = t * 64 + w * 16;
        // ---- layer 2: g1 = relu(m @ W1 + b1) via MFMA ----
        f32x4 acc1[8];
        #pragma unroll
        for (int n = 0; n < 8; ++n) acc1[n] = (f32x4){0.f, 0.f, 0.f, 0.f};
        const unsigned short* arow = M + (size_t)(s0 + lr) * 128 + lg * 8;
        #pragma unroll
        for (int ks = 0; ks < 4; ++ks) {
            bf16x8 af = *(const bf16x8*)(arow + ks * 32);
            #pragma unroll
            for (int n = 0; n < 8; ++n) {
                bf16x8 bf = *(const bf16x8*)&lw1[((ks * 8 + n) * 64 + l) * 8];
                acc1[n] = __builtin_amdgcn_mfma_f32_16x16x32_bf16(af, bf, acc1[n], 0, 0, 0);
            }
        }
        // bounce g1 (C layout) -> LDS row-major [16][128] bf16, XOR-swizzled
        #pragma unroll
        for (int n = 0; n < 8; ++n) {
            #pragma unroll
            for (int r = 0; r < 4; ++r) {
                float g = fmaxf(acc1[n][r] + b1v[n], 0.f);
                int row = lg * 4 + r, col = n * 16 + lr;
                int boff = row * 256 + ((col * 2) ^ ((row & 7) << 4));
                bounce[w][boff >> 1] = f2bf(g);
            }
        }
        // ---- layer 3: g2 = relu(g1 @ W2 + b2) ----
        f32x4 acc2[4];
        #pragma unroll
        for (int n = 0; n < 4; ++n) acc2[n] = (f32x4){0.f, 0.f, 0.f, 0.f};
        #pragma unroll
        for (int ks = 0; ks < 4; ++ks) {
            int roff = lr * 256 + ((ks * 64 + lg * 16) ^ ((lr & 7) << 4));
            bf16x8 af2 = *(const bf16x8*)((const char*)&bounce[w][0] + roff);
            #pragma unroll
            for (int n = 0; n < 4; ++n) {
                bf16x8 bf = *(const bf16x8*)&lw2[((ks * 4 + n) * 64 + l) * 8];
                acc2[n] = __builtin_amdgcn_mfma_f32_16x16x32_bf16(af2, bf, acc2[n], 0, 0, 0);
            }
        }
        // ---- layer 4: dot with w_eff, reduce over 16 lanes, sigmoid ----
        float p0 = 0.f, p1 = 0.f, p2 = 0.f, p3 = 0.f;
        #pragma unroll
        for (int n = 0; n < 4; ++n) {
            p0 += fmaxf(acc2[n][0] + b2v[n], 0.f) * wev[n];
            p1 += fmaxf(acc2[n][1] + b2v[n], 0.f) * wev[n];
            p2 += fmaxf(acc2[n][2] + b2v[n], 0.f) * wev[n];
            p3 += fmaxf(acc2[n][3] + b2v[n], 0.f) * wev[n];
        }
        #pragma unroll
        for (int m = 1; m < 16; m <<= 1) {
            p0 += __shfl_xor(p0, m);
            p1 += __shfl_xor(p1, m);
            p2 += __shfl_xor(p2, m);
            p3 += __shfl_xor(p3, m);
        }
        float s0f = 1.f / (1.f + expf(-(p0 + bo)));
        float s1f = 1.f / (1.f + expf(-(p1 + bo)));
        float s2f = 1.f / (1.f + expf(-(p2 + bo)));
        float s3f = 1.f / (1.f + expf(-(p3 + bo)));
        if (lr < 4) {
            float v = (lr == 0) ? s0f : (lr == 1) ? s1f : (lr == 2) ? s2f : s3f;
            out[s0 + lg * 4 + lr] = v;
        }
    }
}

// ---------------- host launcher ----------------
extern "C" void kernel_launch(void* const* d_in, const int* in_sizes, int n_in,
                              void* d_out, int out_size, void* d_ws, size_t ws_size,
                              hipStream_t stream) {
    const float* combined = (const float*)d_in[0];
    const float* W_in  = (const float*)d_in[1];
    const float* b_in  = (const float*)d_in[2];
    const float* W1    = (const float*)d_in[3];
    const float* b1    = (const float*)d_in[4];
    const float* W2    = (const float*)d_in[5];
    const float* b2    = (const float*)d_in[6];
    const float* W_out = (const float*)d_in[7];
    const float* b_out = (const float*)d_in[8];
    float* out = (float*)d_out;

    char* ws = (char*)d_ws;
    unsigned short* M    = (unsigned short*)(ws + WS_M);
    unsigned short* fWin = (unsigned short*)(ws + WS_WIN);
    unsigned short* fW1  = (unsigned short*)(ws + WS_W1);
    unsigned short* fW2  = (unsigned short*)(ws + WS_W2);
    float* weff          = (float*)(ws + WS_WEFF);

    prep_kernel<<<(65536 + 16384 + 8192 + 64 + 255) / 256, 256, 0, stream>>>(
        W_in, W1, W2, W_out, fWin, fW1, fW2, weff);
    kA<<<256, 1024, 0, stream>>>(combined, fWin, b_in, M);
    kB<<<512, 256, 0, stream>>>(M, fW1, fW2, weff, b1, b2, b_out, out);
}

// Round 4
// 279.408 us; speedup vs baseline: 4.2654x; 4.2637x over previous
//
#include <hip/hip_runtime.h>
#include <hip/hip_bf16.h>
#include <cstdint>
#include <cstddef>

// BaseNet: B=262144 samples, d=512.
// H = relu(reshape(combined,[2B,512]) @ W_in + b_in)   [2B,128]
// m[s] = 0.5*(H[2s]+H[2s+1])                           [B,128]
// g1 = relu(m @ W1 + b1); g2 = relu(g1 @ W2 + b2)      [B,128],[B,64]
// out = sigmoid(g2 . (W_out[:64]+W_out[64:]) + b_out)  [B]

#define NROWS   524288   // 2B
#define NSAMP   262144   // B

typedef __attribute__((ext_vector_type(8))) short  bf16x8;
typedef __attribute__((ext_vector_type(4))) float  f32x4;

__device__ __forceinline__ unsigned short f2bf(float f) {
    unsigned u = __float_as_uint(f);
    u += 0x7fffu + ((u >> 16) & 1u);   // round-to-nearest-even
    return (unsigned short)(u >> 16);
}

__device__ __forceinline__ bf16x8 cvt8(f32x4 lo, f32x4 hi) {
    bf16x8 r;
    r[0] = (short)f2bf(lo[0]); r[1] = (short)f2bf(lo[1]);
    r[2] = (short)f2bf(lo[2]); r[3] = (short)f2bf(lo[3]);
    r[4] = (short)f2bf(hi[0]); r[5] = (short)f2bf(hi[1]);
    r[6] = (short)f2bf(hi[2]); r[7] = (short)f2bf(hi[3]);
    return r;
}

// ---------------- workspace layout (bytes) ----------------
#define WS_M     0                       // [B][128] bf16 = 67108864 B
#define WS_WIN   67108864                // Win frags: 16*8*64*8 bf16 = 131072 B
#define WS_W1    67239936                // W1 frags:  4*8*64*8 bf16 = 32768 B
#define WS_W2    67272704                // W2 frags:  4*4*64*8 bf16 = 16384 B
#define WS_WEFF  67289088                // 64 floats

// ---------------- prep: pack weights to MFMA B-fragment layout ----------------
// Standard B-frag (16x16x32): lane l holds B[k=(l>>4)*8+j][col=l&15], j=0..7.
// fWin uses a PERMUTED k mapping to match kA's coalesced A loads:
//   slot j of lane (lg=l>>4) holds k = (j<4) ? lg*4+j : 16+lg*4+(j-4)  (within 32-group)
__global__ void prep_kernel(const float* __restrict__ W_in,
                            const float* __restrict__ W1,
                            const float* __restrict__ W2,
                            const float* __restrict__ W_out,
                            unsigned short* __restrict__ fWin,
                            unsigned short* __restrict__ fW1,
                            unsigned short* __restrict__ fW2,
                            float* __restrict__ weff) {
    int tid = blockIdx.x * 256 + threadIdx.x;
    if (tid < 65536) {                       // W_in [512][128]: KT=16, NT=8 (permuted k)
        int e = tid;
        int j = e & 7, l = (e >> 3) & 63, rest = e >> 9;
        int n = rest & 7, kt = rest >> 3;
        int lg = l >> 4;
        int kin = (j < 4) ? (lg * 4 + j) : (16 + lg * 4 + (j - 4));
        int k = kt * 32 + kin;
        int col = n * 16 + (l & 15);
        fWin[e] = f2bf(W_in[k * 128 + col]);
    } else if (tid < 65536 + 16384) {        // W1 [128][128]: KT=4, NT=8 (standard)
        int e = tid - 65536;
        int j = e & 7, l = (e >> 3) & 63, rest = e >> 9;
        int n = rest & 7, kt = rest >> 3;
        int k = kt * 32 + ((l >> 4) << 3) + j;
        int col = n * 16 + (l & 15);
        fW1[e] = f2bf(W1[k * 128 + col]);
    } else if (tid < 65536 + 16384 + 8192) { // W2 [128][64]: KT=4, NT=4 (standard)
        int e = tid - 65536 - 16384;
        int j = e & 7, l = (e >> 3) & 63, rest = e >> 9;
        int n = rest & 3, kt = rest >> 2;
        int k = kt * 32 + ((l >> 4) << 3) + j;
        int col = n * 16 + (l & 15);
        fW2[e] = f2bf(W2[k * 64 + col]);
    } else if (tid < 65536 + 16384 + 8192 + 64) {
        int c = tid - (65536 + 16384 + 8192);
        weff[c] = W_out[c] + W_out[64 + c];
    }
}

// ---------------- kernel A: big GEMM + bias/relu + node-mean -> M (bf16) -----
// 256 persistent blocks (1/CU: 145KB LDS), 512 threads = 8 waves (2/SIMD).
// amdgpu_waves_per_eu(2,2): min=max=2 waves/EU pins the VGPR budget at 256
// (round-3 lesson: launch_bounds' 2nd arg is only a CAP; the allocator shrank
// to 64 arch VGPR chasing unattainable occupancy and spilled everything).
// A loads: permuted-k mapping -> each load = 16 rows x 64B contiguous.
// Triple-buffered staging (prefetch distance 2 chunks): ~16 x 1KB loads in
// flight per wave so 8 waves/CU can still saturate HBM.
// M writes: bounce C-frags through per-wave LDS, store 1KB contiguous lines.
__global__ void __launch_bounds__(512) __attribute__((amdgpu_waves_per_eu(2, 2)))
kA(const float* __restrict__ A,              // [2B][512] fp32 (= combined)
   const unsigned short* __restrict__ fWin,  // frag layout (permuted k)
   const float* __restrict__ b_in,
   unsigned short* __restrict__ M) {         // [B][128] bf16
    __shared__ unsigned short lwin[65536];    // 128 KB
    __shared__ unsigned short bounce[8][1088];// 8 waves x 8 rows x 272B = 17 KB
    {
        const f32x4* src = (const f32x4*)fWin;
        f32x4* dst = (f32x4*)lwin;
        int tid = threadIdx.x;
        #pragma unroll
        for (int i = 0; i < 16; ++i) dst[i * 512 + tid] = src[i * 512 + tid];
    }
    __syncthreads();
    const int w = threadIdx.x >> 6, l = threadIdx.x & 63;
    const int lr = l & 15, lg = l >> 4;
    float binv[8];
    #pragma unroll
    for (int n = 0; n < 8; ++n) binv[n] = b_in[n * 16 + lr];
    unsigned short* bw = &bounce[w][0];

    for (int t = blockIdx.x; t < NROWS / 256; t += 256) {
        const size_t rowbase = (size_t)t * 256 + (size_t)w * 32;  // wave: 32 rows
        const float* a0 = A + (rowbase + lr) * 512 + lg * 4;
        const float* a1 = a0 + (size_t)16 * 512;

        f32x4 acc[2][8];
        #pragma unroll
        for (int rt = 0; rt < 2; ++rt)
            #pragma unroll
            for (int n = 0; n < 8; ++n) acc[rt][n] = (f32x4){0.f, 0.f, 0.f, 0.f};

        // triple-buffered staging: [buf][rowtile][ks][half], chunk = 64 floats
        f32x4 st[3][2][2][2];
        #pragma unroll
        for (int pc = 0; pc < 2; ++pc) {
            #pragma unroll
            for (int ks = 0; ks < 2; ++ks) {
                st[pc][0][ks][0] = *(const f32x4*)(a0 + pc * 64 + ks * 32);
                st[pc][0][ks][1] = *(const f32x4*)(a0 + pc * 64 + ks * 32 + 16);
                st[pc][1][ks][0] = *(const f32x4*)(a1 + pc * 64 + ks * 32);
                st[pc][1][ks][1] = *(const f32x4*)(a1 + pc * 64 + ks * 32 + 16);
            }
        }
        #pragma unroll
        for (int c = 0; c < 8; ++c) {           // 8 chunks x 64 floats
            const int cb = c % 3;
            if (c < 6) {
                const int nb = (c + 2) % 3;
                #pragma unroll
                for (int ks = 0; ks < 2; ++ks) {
                    st[nb][0][ks][0] = *(const f32x4*)(a0 + (c + 2) * 64 + ks * 32);
                    st[nb][0][ks][1] = *(const f32x4*)(a0 + (c + 2) * 64 + ks * 32 + 16);
                    st[nb][1][ks][0] = *(const f32x4*)(a1 + (c + 2) * 64 + ks * 32);
                    st[nb][1][ks][1] = *(const f32x4*)(a1 + (c + 2) * 64 + ks * 32 + 16);
                }
            }
            #pragma unroll
            for (int ks = 0; ks < 2; ++ks) {
                const int kg = c * 2 + ks;
                bf16x8 af0 = cvt8(st[cb][0][ks][0], st[cb][0][ks][1]);
                bf16x8 af1 = cvt8(st[cb][1][ks][0], st[cb][1][ks][1]);
                #pragma unroll
                for (int n = 0; n < 8; ++n) {
                    bf16x8 bf = *(const bf16x8*)&lwin[((kg * 8 + n) * 64 + l) * 8];
                    acc[0][n] = __builtin_amdgcn_mfma_f32_16x16x32_bf16(af0, bf, acc[0][n], 0, 0, 0);
                    acc[1][n] = __builtin_amdgcn_mfma_f32_16x16x32_bf16(af1, bf, acc[1][n], 0, 0, 0);
                }
            }
        }
        // epilogue: bias+relu+pair-mean -> LDS bounce -> 1KB contiguous stores.
        // C layout: row=(l>>4)*4+r, col=l&15; rows 2s,2s+1 pair to sample s.
        // bounce row stride 272B (=136 shorts) keeps b128 readback 2-way max.
        #pragma unroll
        for (int rt = 0; rt < 2; ++rt) {
            #pragma unroll
            for (int n = 0; n < 8; ++n) {
                const float b = binv[n];
                float h0 = fmaxf(acc[rt][n][0] + b, 0.f);
                float h1 = fmaxf(acc[rt][n][1] + b, 0.f);
                float h2 = fmaxf(acc[rt][n][2] + b, 0.f);
                float h3 = fmaxf(acc[rt][n][3] + b, 0.f);
                bw[(2 * lg) * 136 + n * 16 + lr]     = f2bf(0.5f * (h0 + h1));
                bw[(2 * lg + 1) * 136 + n * 16 + lr] = f2bf(0.5f * (h2 + h3));
            }
            asm volatile("s_waitcnt lgkmcnt(0)" ::: "memory");  // same-wave write->read
            const size_t sampbase = (rowbase >> 1) + rt * 8;
            #pragma unroll
            for (int r = 0; r < 2; ++r) {
                int ci = r * 64 + l;
                int s = ci >> 4, cc = ci & 15;
                bf16x8 v = *(const bf16x8*)&bw[s * 136 + cc * 8];
                *(bf16x8*)&M[(sampbase + s) * 128 + cc * 8] = v;
            }
            // reads' lgkm wait precedes the stores (data dep), so rt=1's
            // bounce overwrite is safely ordered after rt=0's readback.
        }
    }
}

// ---------------- kernel B: m -> g1 -> g2 -> sigmoid(score) -----------------
// 512 blocks (2/CU, LDS=64KB), 4 waves x 16 samples per tile-iter.
__global__ void __launch_bounds__(256, 2)
kB(const unsigned short* __restrict__ M,
   const unsigned short* __restrict__ fW1,
   const unsigned short* __restrict__ fW2,
   const float* __restrict__ weff,
   const float* __restrict__ b1,
   const float* __restrict__ b2,
   const float* __restrict__ b_out,
   float* __restrict__ out) {
    __shared__ unsigned short lw1[16384];       // 32 KB
    __shared__ unsigned short lw2[8192];        // 16 KB
    __shared__ unsigned short bounce[4][2048];  // 4 waves x 4 KB
    {
        int tid = threadIdx.x;
        const f32x4* s1 = (const f32x4*)fW1;
        f32x4* d1 = (f32x4*)lw1;
        #pragma unroll
        for (int i = 0; i < 8; ++i) d1[i * 256 + tid] = s1[i * 256 + tid];
        const f32x4* s2 = (const f32x4*)fW2;
        f32x4* d2 = (f32x4*)lw2;
        #pragma unroll
        for (int i = 0; i < 4; ++i) d2[i * 256 + tid] = s2[i * 256 + tid];
    }
    __syncthreads();
    const int w = threadIdx.x >> 6, l = threadIdx.x & 63;
    const int lr = l & 15, lg = l >> 4;
    float b1v[8], b2v[4], wev[4];
    #pragma unroll
    for (int n = 0; n < 8; ++n) b1v[n] = b1[n * 16 + lr];
    #pragma unroll
    for (int n = 0; n < 4; ++n) { b2v[n] = b2[n * 16 + lr]; wev[n] = weff[n * 16 + lr]; }
    const float bo = b_out[0];

    for (int t = blockIdx.x; t < NSAMP / 64; t += 512) {
        const int s0 = t * 64 + w * 16;
        // ---- layer 2: g1 = relu(m @ W1 + b1) via MFMA ----
        f32x4 acc1[8];
        #pragma unroll
        for (int n = 0; n < 8; ++n) acc1[n] = (f32x4){0.f, 0.f, 0.f, 0.f};
        const unsigned short* arow = M + (size_t)(s0 + lr) * 128 + lg * 8;
        #pragma unroll
        for (int ks = 0; ks < 4; ++ks) {
            bf16x8 af = *(const bf16x8*)(arow + ks * 32);
            #pragma unroll
            for (int n = 0; n < 8; ++n) {
                bf16x8 bf = *(const bf16x8*)&lw1[((ks * 8 + n) * 64 + l) * 8];
                acc1[n] = __builtin_amdgcn_mfma_f32_16x16x32_bf16(af, bf, acc1[n], 0, 0, 0);
            }
        }
        // bounce g1 (C layout) -> LDS row-major [16][128] bf16, XOR-swizzled
        #pragma unroll
        for (int n = 0; n < 8; ++n) {
            #pragma unroll
            for (int r = 0; r < 4; ++r) {
                float g = fmaxf(acc1[n][r] + b1v[n], 0.f);
                int row = lg * 4 + r, col = n * 16 + lr;
                int boff = row * 256 + ((col * 2) ^ ((row & 7) << 4));
                bounce[w][boff >> 1] = f2bf(g);
            }
        }
        // ---- layer 3: g2 = relu(g1 @ W2 + b2) ----
        f32x4 acc2[4];
        #pragma unroll
        for (int n = 0; n < 4; ++n) acc2[n] = (f32x4){0.f, 0.f, 0.f, 0.f};
        #pragma unroll
        for (int ks = 0; ks < 4; ++ks) {
            int roff = lr * 256 + ((ks * 64 + lg * 16) ^ ((lr & 7) << 4));
            bf16x8 af2 = *(const bf16x8*)((const char*)&bounce[w][0] + roff);
            #pragma unroll
            for (int n = 0; n < 4; ++n) {
                bf16x8 bf = *(const bf16x8*)&lw2[((ks * 4 + n) * 64 + l) * 8];
                acc2[n] = __builtin_amdgcn_mfma_f32_16x16x32_bf16(af2, bf, acc2[n], 0, 0, 0);
            }
        }
        // ---- layer 4: dot with w_eff, reduce over 16 lanes, sigmoid ----
        float p0 = 0.f, p1 = 0.f, p2 = 0.f, p3 = 0.f;
        #pragma unroll
        for (int n = 0; n < 4; ++n) {
            p0 += fmaxf(acc2[n][0] + b2v[n], 0.f) * wev[n];
            p1 += fmaxf(acc2[n][1] + b2v[n], 0.f) * wev[n];
            p2 += fmaxf(acc2[n][2] + b2v[n], 0.f) * wev[n];
            p3 += fmaxf(acc2[n][3] + b2v[n], 0.f) * wev[n];
        }
        #pragma unroll
        for (int m = 1; m < 16; m <<= 1) {
            p0 += __shfl_xor(p0, m);
            p1 += __shfl_xor(p1, m);
            p2 += __shfl_xor(p2, m);
            p3 += __shfl_xor(p3, m);
        }
        float s0f = 1.f / (1.f + expf(-(p0 + bo)));
        float s1f = 1.f / (1.f + expf(-(p1 + bo)));
        float s2f = 1.f / (1.f + expf(-(p2 + bo)));
        float s3f = 1.f / (1.f + expf(-(p3 + bo)));
        if (lr < 4) {
            float v = (lr == 0) ? s0f : (lr == 1) ? s1f : (lr == 2) ? s2f : s3f;
            out[s0 + lg * 4 + lr] = v;
        }
    }
}

// ---------------- host launcher ----------------
extern "C" void kernel_launch(void* const* d_in, const int* in_sizes, int n_in,
                              void* d_out, int out_size, void* d_ws, size_t ws_size,
                              hipStream_t stream) {
    const float* combined = (const float*)d_in[0];
    const float* W_in  = (const float*)d_in[1];
    const float* b_in  = (const float*)d_in[2];
    const float* W1    = (const float*)d_in[3];
    const float* b1    = (const float*)d_in[4];
    const float* W2    = (const float*)d_in[5];
    const float* b2    = (const float*)d_in[6];
    const float* W_out = (const float*)d_in[7];
    const float* b_out = (const float*)d_in[8];
    float* out = (float*)d_out;

    char* ws = (char*)d_ws;
    unsigned short* M    = (unsigned short*)(ws + WS_M);
    unsigned short* fWin = (unsigned short*)(ws + WS_WIN);
    unsigned short* fW1  = (unsigned short*)(ws + WS_W1);
    unsigned short* fW2  = (unsigned short*)(ws + WS_W2);
    float* weff          = (float*)(ws + WS_WEFF);

    prep_kernel<<<(65536 + 16384 + 8192 + 64 + 255) / 256, 256, 0, stream>>>(
        W_in, W1, W2, W_out, fWin, fW1, fW2, weff);
    kA<<<256, 512, 0, stream>>>(combined, fWin, b_in, M);
    kB<<<512, 256, 0, stream>>>(M, fW1, fW2, weff, b1, b2, b_out, out);
}